// Round 1
// baseline (37116.690 us; speedup 1.0000x reference)
//
#include <hip/hip_runtime.h>
#include <hip/hip_cooperative_groups.h>

namespace cg = cooperative_groups;

#define NZ   512
#define NXX  512
#define NT   1200
#define NSRC 4
#define NREC 512
#define DTC  0.001f
#define DHC  10.0f

// One thread per cell. 256 blocks x 1024 threads = 262144 threads = NZ*NX.
// Leapfrog in-place double buffer: step t reads neighbors from cur_g, writes
// new value into new_g (which holds u_{t-2}, only ever re-read by the owning
// thread). One grid.sync() per step orders writes before next step's reads.
__global__ __launch_bounds__(1024, 1)
void wave_coop(const float* __restrict__ xsrc,   // (NSRC, NT)
               const float* __restrict__ vel,    // (NZ, NX)
               const int*   __restrict__ src_z,  // (NSRC)
               const int*   __restrict__ src_x,  // (NSRC)
               const int*   __restrict__ rec_z,  // (NREC)
               const int*   __restrict__ rec_x,  // (NREC)
               float*       __restrict__ out,    // (NT, NREC)
               float*       __restrict__ buf0,
               float*       __restrict__ buf1)
{
    cg::grid_group grid = cg::this_grid();
    const int gtid = blockIdx.x * blockDim.x + threadIdx.x;
    const int z  = gtid >> 9;          // row    (NX == 512)
    const int xx = gtid & (NXX - 1);   // column

    const float v    = vel[gtid];
    const float coef = (v * DTC) * (v * DTC) / (DHC * DHC);

    // Which sources (if any) live at this cell. Mask so duplicate source
    // positions accumulate, matching jnp .at[].add semantics.
    int smask = 0;
#pragma unroll
    for (int s = 0; s < NSRC; ++s)
        if (src_z[s] == z && src_x[s] == xx) smask |= (1 << s);

    // Receiver ownership: thread r < NREC gathers receiver r each step.
    int rpos = -1;
    if (gtid < NREC) rpos = rec_z[gtid] * NXX + rec_x[gtid];

    float cur = 0.0f, prev = 0.0f;
    float* cur_g = buf0;
    float* new_g = buf1;

    // Zero the initial "current" field (ws is poisoned; buf1 is fully written
    // in step 0 before it is ever read).
    cur_g[gtid] = 0.0f;
    grid.sync();

    for (int t = 0; t < NT; ++t) {
        const float up = (z  > 0      ) ? cur_g[gtid - NXX] : 0.0f;
        const float dn = (z  < NZ  - 1) ? cur_g[gtid + NXX] : 0.0f;
        const float lf = (xx > 0      ) ? cur_g[gtid - 1  ] : 0.0f;
        const float rt = (xx < NXX - 1) ? cur_g[gtid + 1  ] : 0.0f;

        float nw = 2.0f * cur - prev + coef * (up + dn + lf + rt - 4.0f * cur);

        if (smask) {
#pragma unroll
            for (int s = 0; s < NSRC; ++s)
                if (smask & (1 << s)) nw += xsrc[s * NT + t];
        }

        new_g[gtid] = nw;
        prev = cur;
        cur  = nw;

        grid.sync();  // all writes of step t visible grid-wide

        // Gather receivers for step t. new_g is next overwritten in step t+2,
        // which is behind the sync at the end of step t+1 -> race-free.
        if (rpos >= 0) out[t * NREC + gtid] = new_g[rpos];

        float* tmp = cur_g; cur_g = new_g; new_g = tmp;
    }
}

extern "C" void kernel_launch(void* const* d_in, const int* in_sizes, int n_in,
                              void* d_out, int out_size, void* d_ws, size_t ws_size,
                              hipStream_t stream) {
    const float* xsrc  = (const float*)d_in[0];
    const float* vel   = (const float*)d_in[1];
    const int*   src_z = (const int*)  d_in[2];
    const int*   src_x = (const int*)  d_in[3];
    const int*   rec_z = (const int*)  d_in[4];
    const int*   rec_x = (const int*)  d_in[5];
    float*       out   = (float*)d_out;

    float* buf0 = (float*)d_ws;
    float* buf1 = buf0 + NZ * NXX;

    void* args[] = {(void*)&xsrc, (void*)&vel, (void*)&src_z, (void*)&src_x,
                    (void*)&rec_z, (void*)&rec_x, (void*)&out, (void*)&buf0,
                    (void*)&buf1};

    dim3 grid(256), block(1024);
    hipLaunchCooperativeKernel((const void*)wave_coop, grid, block, args, 0, stream);
}

// Round 2
// 4188.711 us; speedup vs baseline: 8.8611x; 8.8611x over previous
//
#include <hip/hip_runtime.h>
#include <hip/hip_cooperative_groups.h>

namespace cg = cooperative_groups;

#define NZg  512
#define NXg  512
#define NT   1200
#define NSRC 4
#define NREC 512
#define DTC  0.001f
#define DHC  10.0f

#define TILE     32           // interior tile per block
#define KK       16           // time steps per batch (= halo width)
#define EE       64           // extended tile = TILE + 2*KK
#define NBATCH   75           // NT / KK
#define NTHREADS 256
#define CPT      16           // cells per thread = EE*EE / NTHREADS

// Temporal-blocked 2D acoustic FDTD.
// 256 blocks (16x16 tiles) x 256 threads. Per grid-sync batch: load 64x64
// extended tile (cur,prev as float2), run 16 leapfrog steps in LDS (halo
// erodes 1 cell/step -> 32x32 interior exact after 16), write interior back.
// Ping-pong global slots -> one grid.sync() per batch (75+1 total vs 1200).
__global__ __launch_bounds__(256, 1)
void wave_tb(const float* __restrict__ xsrc,   // (NSRC, NT)
             const float* __restrict__ vel,    // (NZ, NX)
             const int*   __restrict__ src_z,
             const int*   __restrict__ src_x,
             const int*   __restrict__ rec_z,
             const int*   __restrict__ rec_x,
             float*       __restrict__ out,    // (NT, NREC)
             float2*      __restrict__ slot0,  // (cur, prev) packed
             float2*      __restrict__ slot1)
{
    cg::grid_group grid = cg::this_grid();

    __shared__ float sA[EE * EE];   // write target / becomes cur
    __shared__ float sB[EE * EE];   // read (cur) source
    __shared__ int   recl[NREC];
    __shared__ int   nrec;

    const int tid = threadIdx.x;
    const int bz  = blockIdx.x >> 4;
    const int bx  = blockIdx.x & 15;
    const int oz  = bz * TILE - KK;            // extended-tile origin (may be <0)
    const int ox  = bx * TILE - KK;
    const int lx0 = tid & (EE - 1);            // thread's fixed column in tile
    const int r0  = tid >> 6;                  // base row; cell i is row r0+4i

    // ---- zero ping-pong slot 0 (batch 0 reads it) ----
    {
        const int g0 = blockIdx.x * NTHREADS + tid;
#pragma unroll
        for (int i = 0; i < 4; ++i)
            slot0[g0 + i * 65536] = make_float2(0.f, 0.f);
    }

    // ---- receiver list for this block's interior ----
    if (tid == 0) nrec = 0;
    __syncthreads();
    for (int r = tid; r < NREC; r += NTHREADS) {
        const int rz = rec_z[r], rx = rec_x[r];
        if (rz >= bz * TILE && rz < bz * TILE + TILE &&
            rx >= bx * TILE && rx < bx * TILE + TILE) {
            const int lz = rz - oz, lx = rx - ox;     // in [KK, KK+TILE)
            const int s  = atomicAdd(&nrec, 1);
            recl[s] = (r << 16) | (lz << 8) | lx;
        }
    }

    // ---- per-cell coefficient (registers) + source bitmask ----
    float coefr[CPT];
    unsigned long long smask = 0ull;
    int szr[NSRC], sxr[NSRC];
#pragma unroll
    for (int s = 0; s < NSRC; ++s) { szr[s] = src_z[s]; sxr[s] = src_x[s]; }
#pragma unroll
    for (int i = 0; i < CPT; ++i) {
        const int lz = r0 + 4 * i;
        const int gz = oz + lz, gx = ox + lx0;
        const bool inside = (gz >= 0 && gz < NZg && gx >= 0 && gx < NXg);
        const float v = inside ? vel[gz * NXg + gx] : 0.f;
        const float c = v * DTC;
        coefr[i] = (c * c) / (DHC * DHC);
#pragma unroll
        for (int s = 0; s < NSRC; ++s)
            if (inside && szr[s] == gz && sxr[s] == gx)
                smask |= (1ull << (i * NSRC + s));
    }
    __syncthreads();        // recl/nrec ready
    grid.sync();            // slot0 zeroed everywhere

    float* pa = sA;         // write target this sub-step
    float* pb = sB;         // current field (neighbor reads)

    float own[CPT];         // u_t   at thread's cells
    float prv[CPT];         // u_{t-1}

    for (int batch = 0; batch < NBATCH; ++batch) {
        const float2* gin  = (batch & 1) ? slot1 : slot0;
        float2*       gout = (batch & 1) ? slot0 : slot1;

        // ---- load extended tile: cur -> pb + own regs, prev -> prv regs ----
#pragma unroll
        for (int i = 0; i < CPT; ++i) {
            const int c  = tid + NTHREADS * i;
            const int lz = r0 + 4 * i;
            const int gz = oz + lz, gx = ox + lx0;
            if (gz >= 0 && gz < NZg && gx >= 0 && gx < NXg) {
                const float2 v = gin[gz * NXg + gx];
                pb[c] = v.x;  own[i] = v.x;  prv[i] = v.y;
            } else {
                pb[c] = 0.f;  pa[c] = 0.f;   // out-of-domain stays exactly 0
                own[i] = 0.f; prv[i] = 0.f;
            }
        }
        __syncthreads();

        // ---- KK leapfrog sub-steps in LDS ----
        for (int j = 0; j < KK; ++j) {
            const int t = batch * KK + j;
#pragma unroll
            for (int i = 0; i < CPT; ++i) {
                const int c  = tid + NTHREADS * i;
                const int lz = r0 + 4 * i;
                const bool rim = (lz == 0) | (lz == EE - 1) |
                                 (lx0 == 0) | (lx0 == EE - 1);
                const int gz = oz + lz, gx = ox + lx0;
                const bool inside = (gz >= 0 && gz < NZg && gx >= 0 && gx < NXg);
                if (!rim && inside) {
                    const float o   = own[i];
                    const float lap = pb[c - EE] + pb[c + EE] +
                                      pb[c - 1]  + pb[c + 1] - 4.f * o;
                    float nw = 2.f * o - prv[i] + coefr[i] * lap;
                    const unsigned int mm =
                        (unsigned int)(smask >> (i * NSRC)) & 15u;
                    if (mm) {
#pragma unroll
                        for (int s = 0; s < NSRC; ++s)
                            if (mm & (1u << s)) nw += xsrc[s * NT + t];
                    }
                    pa[c]  = nw;
                    prv[i] = o;
                    own[i] = nw;
                }
            }
            __syncthreads();
            // receivers: pa holds u_{t+1} == h_new at step t (valid on interior)
            for (int r = tid; r < nrec; r += NTHREADS) {
                const int e = recl[r];
                out[t * NREC + (e >> 16)] = pa[((e >> 8) & 255) * EE + (e & 255)];
            }
            float* tmp = pa; pa = pb; pb = tmp;
        }

        // ---- write back interior (rows 16..47 -> i in [4,12)) ----
        if (lx0 >= KK && lx0 < KK + TILE) {
#pragma unroll
            for (int i = 4; i < 12; ++i) {
                const int gz = oz + r0 + 4 * i;
                const int gx = ox + lx0;
                gout[gz * NXg + gx] = make_float2(own[i], prv[i]);
            }
        }
        grid.sync();
    }
}

extern "C" void kernel_launch(void* const* d_in, const int* in_sizes, int n_in,
                              void* d_out, int out_size, void* d_ws, size_t ws_size,
                              hipStream_t stream) {
    const float* xsrc  = (const float*)d_in[0];
    const float* vel   = (const float*)d_in[1];
    const int*   src_z = (const int*)  d_in[2];
    const int*   src_x = (const int*)  d_in[3];
    const int*   rec_z = (const int*)  d_in[4];
    const int*   rec_x = (const int*)  d_in[5];
    float*       out   = (float*)d_out;

    float2* slot0 = (float2*)d_ws;
    float2* slot1 = slot0 + NZg * NXg;

    void* args[] = {(void*)&xsrc, (void*)&vel, (void*)&src_z, (void*)&src_x,
                    (void*)&rec_z, (void*)&rec_x, (void*)&out,
                    (void*)&slot0, (void*)&slot1};

    dim3 grid(256), block(NTHREADS);
    hipLaunchCooperativeKernel((const void*)wave_tb, grid, block, args, 0, stream);
}

// Round 3
// 3925.402 us; speedup vs baseline: 9.4555x; 1.0671x over previous
//
#include <hip/hip_runtime.h>
#include <hip/hip_cooperative_groups.h>

namespace cg = cooperative_groups;

#define NZg  512
#define NXg  512
#define NT   1200
#define NSRC 4
#define NREC 512
#define DTC  0.001f
#define DHC  10.0f

#define TILE   32            // interior tile per block
#define KK     16            // substeps per batch (= halo width), even
#define EE     64            // extended tile = TILE + 2*KK
#define EEP    (EE + 2)      // +2 padding rows (zeroed once)
#define NBATCH 75            // NT / KK
#define NTH    512           // 8 waves

// Temporal-blocked FDTD with point-to-point neighbor flag sync.
// 256 blocks (16x16 tiles) x 512 threads, 1 block/CU. Per batch: wait 8
// neighbors' flags >= b, load 64x64 halo tile, 16 leapfrog substeps in LDS
// (branch-free: rim computes erosion-covered garbage, out-of-domain cells
// pinned to 0 via coef=0), write 32x32 interior back, fence + set flag.
__global__ __launch_bounds__(NTH, 1)
void wave_nb(const float* __restrict__ xsrc,   // (NSRC, NT)
             const float* __restrict__ vel,    // (NZ, NX)
             const int*   __restrict__ src_z,
             const int*   __restrict__ src_x,
             const int*   __restrict__ rec_z,
             const int*   __restrict__ rec_x,
             float*       __restrict__ out,    // (NT, NREC)
             float2*      __restrict__ slot0,  // (cur, prev)
             float2*      __restrict__ slot1,
             int*         __restrict__ flags)  // (256)
{
    cg::grid_group grid = cg::this_grid();

    __shared__ float sA[EEP * EE];
    __shared__ float sB[EEP * EE];
    __shared__ float sx[NSRC * NT];
    __shared__ int   recl[NREC];
    __shared__ int   nrec_s;

    const int tid = threadIdx.x;
    const int me  = blockIdx.x;
    const int bz  = me >> 4, bx = me & 15;
    const int oz  = bz * TILE - KK;
    const int ox  = bx * TILE - KK;
    const int pc  = tid & 31;        // pair column: cells 2pc, 2pc+1
    const int r0  = tid >> 5;        // 0..15; rows r0 + 16*i
    const int lx  = 2 * pc;

    // Reset my flag (stale values survive between graph replays).
    if (tid == 0) { flags[me] = 0; nrec_s = 0; }

    // Zero LDS padding rows (rows 0 and EEP-1 of both buffers) once.
    if (tid < 2 * EE) {
        const int r = (tid < EE) ? 0 : (EEP - 1);
        const int c = tid & (EE - 1);
        sA[r * EE + c] = 0.f;  sB[r * EE + c] = 0.f;
    }
    // Stage source traces in LDS.
    for (int i = tid; i < NSRC * NT; i += NTH) sx[i] = xsrc[i];
    __syncthreads();

    // Receiver list for this block's interior.
    for (int r = tid; r < NREC; r += NTH) {
        const int rz = rec_z[r], rx = rec_x[r];
        if (rz >= bz * TILE && rz < bz * TILE + TILE &&
            rx >= bx * TILE && rx < bx * TILE + TILE) {
            const int lzp = rz - oz + 1;          // padded row
            const int lxx = rx - ox;
            const int s = atomicAdd(&nrec_s, 1);
            recl[s] = (r << 16) | (lzp << 8) | lxx;
        }
    }

    // Per-cell coefficient (coef=0 out-of-domain pins those cells to 0).
    float2 coef[4];
    unsigned int smask = 0;
    int szr[NSRC], sxr[NSRC];
#pragma unroll
    for (int s = 0; s < NSRC; ++s) { szr[s] = src_z[s]; sxr[s] = src_x[s]; }
#pragma unroll
    for (int i = 0; i < 4; ++i) {
        const int gz = oz + r0 + 16 * i;
        const int gx = ox + lx;                  // even; pair never straddles
        const bool in = (gz >= 0 && gz < NZg && gx >= 0 && gx < NXg);
        const float2 v = in ? *(const float2*)&vel[gz * NXg + gx]
                            : make_float2(0.f, 0.f);
        coef[i].x = (v.x * DTC) * (v.x * DTC) / (DHC * DHC);
        coef[i].y = (v.y * DTC) * (v.y * DTC) / (DHC * DHC);
        if (in) {
#pragma unroll
            for (int s = 0; s < NSRC; ++s) {
                if (szr[s] == gz && sxr[s] == gx)     smask |= 1u << (i * 8 + s);
                if (szr[s] == gz && sxr[s] == gx + 1) smask |= 1u << (i * 8 + 4 + s);
            }
        }
    }
    __syncthreads();
    grid.sync();                 // flags reset everywhere; the ONLY grid sync

    float2 own[4], prv[4];
    const int cb = (r0 + 1) * EE + lx;           // padded LDS base

    // Neighbor for my spin lane (threads 0..8, skip 4 = self).
    bool havenb = false; int nbidx = 0;
    if (tid < 9 && tid != 4) {
        const int nz = bz + tid / 3 - 1, nx = bx + tid % 3 - 1;
        havenb = (nz >= 0 && nz < 16 && nx >= 0 && nx < 16);
        nbidx  = nz * 16 + nx;
    }

    // One leapfrog substep: read src_, write dst_, then receivers gather.
    auto STEP = [&](float* __restrict__ dst_, const float* __restrict__ src_,
                    int t) {
#pragma unroll
        for (int i = 0; i < 4; ++i) {
            const int c = cb + i * 16 * EE;
            const float2 U = *(const float2*)&src_[c - EE];
            const float2 D = *(const float2*)&src_[c + EE];
            const float2 L = *(const float2*)&src_[c - 2];
            const float2 R = *(const float2*)&src_[c + 2];
            const float2 o = own[i], p = prv[i];
            const float lapx = U.x + D.x + L.y + o.y - 4.f * o.x;
            const float lapy = U.y + D.y + o.x + R.x - 4.f * o.y;
            float2 nw;
            nw.x = 2.f * o.x - p.x + coef[i].x * lapx;
            nw.y = 2.f * o.y - p.y + coef[i].y * lapy;
            const unsigned int mm = (smask >> (i * 8)) & 0xFFu;
            if (mm) {
#pragma unroll
                for (int s = 0; s < NSRC; ++s) {
                    if (mm & (1u << s))       nw.x += sx[s * NT + t];
                    if (mm & (1u << (4 + s))) nw.y += sx[s * NT + t];
                }
            }
            *(float2*)&dst_[c] = nw;
            prv[i] = o;  own[i] = nw;
        }
        __syncthreads();
        for (int r = tid; r < nrec_s; r += NTH) {
            const int e = recl[r];
            out[t * NREC + (e >> 16)] = dst_[((e >> 8) & 0xFF) * EE + (e & 0xFF)];
        }
    };

    for (int b = 0; b < NBATCH; ++b) {
        const float2* gin  = (b & 1) ? slot1 : slot0;
        float2*       gout = (b & 1) ? slot0 : slot1;

        // ---- wait for the 8 neighbors to have written batch b-1 ----
        if (b > 0) {
            if (havenb) {
                while (__hip_atomic_load(&flags[nbidx], __ATOMIC_RELAXED,
                                         __HIP_MEMORY_SCOPE_AGENT) < b)
                    __builtin_amdgcn_s_sleep(2);
            }
            __syncthreads();
            __threadfence();     // agent acquire: invalidate stale L1/L2
        }

        // ---- load extended tile into sB + registers ----
#pragma unroll
        for (int i = 0; i < 4; ++i) {
            const int c  = cb + i * 16 * EE;
            const int gz = oz + r0 + 16 * i;
            const int gx = ox + lx;
            if (b > 0 && gz >= 0 && gz < NZg && gx >= 0 && gx < NXg) {
                const float4 v = *(const float4*)&gin[gz * NXg + gx];
                own[i] = make_float2(v.x, v.z);
                prv[i] = make_float2(v.y, v.w);
                *(float2*)&sB[c] = make_float2(v.x, v.z);
            } else {             // batch 0 state is all-zero; or out-of-domain
                own[i] = make_float2(0.f, 0.f);
                prv[i] = make_float2(0.f, 0.f);
                *(float2*)&sB[c] = make_float2(0.f, 0.f);
            }
        }
        __syncthreads();

        // ---- KK substeps, statically ping-ponged ----
        for (int j = 0; j < KK; j += 2) {
            STEP(sA, sB, b * KK + j);
            STEP(sB, sA, b * KK + j + 1);
        }

        // ---- write back 32x32 interior (rows 16..47 -> i in {1,2}) ----
        if (pc >= 8 && pc < 24) {
#pragma unroll
            for (int i = 1; i <= 2; ++i) {
                const int gz = oz + r0 + 16 * i;
                const int gx = ox + lx;
                *(float4*)&gout[gz * NXg + gx] =
                    make_float4(own[i].x, prv[i].x, own[i].y, prv[i].y);
            }
        }
        __syncthreads();         // barrier drains each wave's vmcnt
        if (tid == 0) {
            __threadfence();     // flush XCD L2 to coherence point
            __hip_atomic_store(&flags[me], b + 1, __ATOMIC_RELEASE,
                               __HIP_MEMORY_SCOPE_AGENT);
        }
    }
}

extern "C" void kernel_launch(void* const* d_in, const int* in_sizes, int n_in,
                              void* d_out, int out_size, void* d_ws, size_t ws_size,
                              hipStream_t stream) {
    const float* xsrc  = (const float*)d_in[0];
    const float* vel   = (const float*)d_in[1];
    const int*   src_z = (const int*)  d_in[2];
    const int*   src_x = (const int*)  d_in[3];
    const int*   rec_z = (const int*)  d_in[4];
    const int*   rec_x = (const int*)  d_in[5];
    float*       out   = (float*)d_out;

    float2* slot0 = (float2*)d_ws;
    float2* slot1 = slot0 + NZg * NXg;
    int*    flags = (int*)(slot1 + NZg * NXg);

    void* args[] = {(void*)&xsrc, (void*)&vel, (void*)&src_z, (void*)&src_x,
                    (void*)&rec_z, (void*)&rec_x, (void*)&out,
                    (void*)&slot0, (void*)&slot1, (void*)&flags};

    dim3 grid(256), block(NTH);
    hipLaunchCooperativeKernel((const void*)wave_nb, grid, block, args, 0, stream);
}

// Round 4
// 901.882 us; speedup vs baseline: 41.1547x; 4.3525x over previous
//
#include <hip/hip_runtime.h>
#include <hip/hip_cooperative_groups.h>

namespace cg = cooperative_groups;

#define NZg  512
#define NXg  512
#define NT   1200
#define NSRC 4
#define NREC 512
#define DTC  0.001f
#define DHC  10.0f

#define TILE   32            // interior tile per block
#define KK     16            // substeps per batch (= halo width), even
#define EE     64            // extended tile = TILE + 2*KK
#define EEP    (EE + 2)      // +2 padding rows (zeroed once)
#define NBATCH 75            // NT / KK
#define NTH    512           // 8 waves

typedef unsigned long long u64;

// Relaxed agent-scope atomics: lower to global_load/store with sc0|sc1
// (bypass L1 + non-coherent per-XCD L2; coherent at memory-side L3).
// NO fence instructions -> no per-batch L2 writeback/invalidate.
__device__ __forceinline__ u64 ld_agent(const u64* p) {
    return __hip_atomic_load(p, __ATOMIC_RELAXED, __HIP_MEMORY_SCOPE_AGENT);
}
__device__ __forceinline__ void st_agent(u64* p, u64 v) {
    __hip_atomic_store(p, v, __ATOMIC_RELAXED, __HIP_MEMORY_SCOPE_AGENT);
}
__device__ __forceinline__ u64 pack2(float a, float b) {
    union { float f[2]; u64 u; } c; c.f[0] = a; c.f[1] = b; return c.u;
}
__device__ __forceinline__ float2 unpack2(u64 v) {
    union { u64 u; float f[2]; } c; c.u = v; return make_float2(c.f[0], c.f[1]);
}

// Temporal-blocked FDTD, p2p neighbor flag sync, fence-free.
// 256 blocks (16x16 tiles) x 512 threads. Per batch: spin on 8 neighbor
// flags >= b (relaxed agent), load 64x64 halo tile (agent atomics), 16
// leapfrog substeps in LDS, write 32x32 interior (agent atomics),
// __syncthreads (drains vmcnt), publish flag (relaxed agent).
__global__ __launch_bounds__(NTH, 1)
void wave_nf(const float* __restrict__ xsrc,   // (NSRC, NT)
             const float* __restrict__ vel,    // (NZ, NX)
             const int*   __restrict__ src_z,
             const int*   __restrict__ src_x,
             const int*   __restrict__ rec_z,
             const int*   __restrict__ rec_x,
             float*       __restrict__ out,    // (NT, NREC)
             u64*         __restrict__ slot0,  // (cur, prev) per cell
             u64*         __restrict__ slot1,
             int*         __restrict__ flags)  // (256)
{
    cg::grid_group grid = cg::this_grid();

    __shared__ float sA[EEP * EE];
    __shared__ float sB[EEP * EE];
    __shared__ float sx[NSRC * NT];
    __shared__ int   recl[NREC];
    __shared__ int   nrec_s;

    const int tid = threadIdx.x;
    const int me  = blockIdx.x;
    const int bz  = me >> 4, bx = me & 15;
    const int oz  = bz * TILE - KK;
    const int ox  = bx * TILE - KK;
    const int pc  = tid & 31;        // pair column: cells 2pc, 2pc+1
    const int r0  = tid >> 5;        // 0..15; rows r0 + 16*i
    const int lx  = 2 * pc;

    // Reset my flag (stale values survive between graph replays); made
    // visible grid-wide by the init grid.sync()'s own release/acquire.
    if (tid == 0) { flags[me] = 0; nrec_s = 0; }

    // Zero LDS padding rows (rows 0 and EEP-1 of both buffers) once.
    if (tid < 2 * EE) {
        const int r = (tid < EE) ? 0 : (EEP - 1);
        const int c = tid & (EE - 1);
        sA[r * EE + c] = 0.f;  sB[r * EE + c] = 0.f;
    }
    // Stage source traces in LDS.
    for (int i = tid; i < NSRC * NT; i += NTH) sx[i] = xsrc[i];
    __syncthreads();

    // Receiver list for this block's interior.
    for (int r = tid; r < NREC; r += NTH) {
        const int rz = rec_z[r], rx = rec_x[r];
        if (rz >= bz * TILE && rz < bz * TILE + TILE &&
            rx >= bx * TILE && rx < bx * TILE + TILE) {
            const int lzp = rz - oz + 1;          // padded row
            const int lxx = rx - ox;
            const int s = atomicAdd(&nrec_s, 1);
            recl[s] = (r << 16) | (lzp << 8) | lxx;
        }
    }

    // Per-cell coefficient (coef=0 out-of-domain pins those cells to 0).
    float2 coef[4];
    unsigned int smask = 0;
    int szr[NSRC], sxr[NSRC];
#pragma unroll
    for (int s = 0; s < NSRC; ++s) { szr[s] = src_z[s]; sxr[s] = src_x[s]; }
#pragma unroll
    for (int i = 0; i < 4; ++i) {
        const int gz = oz + r0 + 16 * i;
        const int gx = ox + lx;                  // even; pair never straddles
        const bool in = (gz >= 0 && gz < NZg && gx >= 0 && gx < NXg);
        const float2 v = in ? *(const float2*)&vel[gz * NXg + gx]
                            : make_float2(0.f, 0.f);
        coef[i].x = (v.x * DTC) * (v.x * DTC) / (DHC * DHC);
        coef[i].y = (v.y * DTC) * (v.y * DTC) / (DHC * DHC);
        if (in) {
#pragma unroll
            for (int s = 0; s < NSRC; ++s) {
                if (szr[s] == gz && sxr[s] == gx)     smask |= 1u << (i * 8 + s);
                if (szr[s] == gz && sxr[s] == gx + 1) smask |= 1u << (i * 8 + 4 + s);
            }
        }
    }
    __syncthreads();
    grid.sync();                 // flags reset everywhere; the ONLY grid sync

    float2 own[4], prv[4];
    const int cb = (r0 + 1) * EE + lx;           // padded LDS base

    // Neighbor for my spin lane (threads 0..8, skip 4 = self).
    bool havenb = false; int nbidx = 0;
    if (tid < 9 && tid != 4) {
        const int nz = bz + tid / 3 - 1, nx = bx + tid % 3 - 1;
        havenb = (nz >= 0 && nz < 16 && nx >= 0 && nx < 16);
        nbidx  = nz * 16 + nx;
    }

    // One leapfrog substep: read src_, write dst_, then receivers gather.
    auto STEP = [&](float* __restrict__ dst_, const float* __restrict__ src_,
                    int t) {
#pragma unroll
        for (int i = 0; i < 4; ++i) {
            const int c = cb + i * 16 * EE;
            const float2 U = *(const float2*)&src_[c - EE];
            const float2 D = *(const float2*)&src_[c + EE];
            const float2 L = *(const float2*)&src_[c - 2];
            const float2 R = *(const float2*)&src_[c + 2];
            const float2 o = own[i], p = prv[i];
            const float lapx = U.x + D.x + L.y + o.y - 4.f * o.x;
            const float lapy = U.y + D.y + o.x + R.x - 4.f * o.y;
            float2 nw;
            nw.x = 2.f * o.x - p.x + coef[i].x * lapx;
            nw.y = 2.f * o.y - p.y + coef[i].y * lapy;
            const unsigned int mm = (smask >> (i * 8)) & 0xFFu;
            if (mm) {
#pragma unroll
                for (int s = 0; s < NSRC; ++s) {
                    if (mm & (1u << s))       nw.x += sx[s * NT + t];
                    if (mm & (1u << (4 + s))) nw.y += sx[s * NT + t];
                }
            }
            *(float2*)&dst_[c] = nw;
            prv[i] = o;  own[i] = nw;
        }
        __syncthreads();
        for (int r = tid; r < nrec_s; r += NTH) {
            const int e = recl[r];
            out[t * NREC + (e >> 16)] = dst_[((e >> 8) & 0xFF) * EE + (e & 0xFF)];
        }
    };

    for (int b = 0; b < NBATCH; ++b) {
        const u64* gin  = (b & 1) ? slot1 : slot0;
        u64*       gout = (b & 1) ? slot0 : slot1;

        // ---- wait for the 8 neighbors to have finished batch b-1 ----
        if (b > 0) {
            if (havenb) {
                while (__hip_atomic_load(&flags[nbidx], __ATOMIC_RELAXED,
                                         __HIP_MEMORY_SCOPE_AGENT) < b)
                    __builtin_amdgcn_s_sleep(1);
            }
            __syncthreads();     // spin result broadcast; compiler barrier
        }

        // ---- load extended tile into sB + registers (agent atomics) ----
#pragma unroll
        for (int i = 0; i < 4; ++i) {
            const int c  = cb + i * 16 * EE;
            const int gz = oz + r0 + 16 * i;
            const int gx = ox + lx;
            if (b > 0 && gz >= 0 && gz < NZg && gx >= 0 && gx < NXg) {
                const float2 c0 = unpack2(ld_agent(&gin[gz * NXg + gx]));
                const float2 c1 = unpack2(ld_agent(&gin[gz * NXg + gx + 1]));
                own[i] = make_float2(c0.x, c1.x);
                prv[i] = make_float2(c0.y, c1.y);
                *(float2*)&sB[c] = own[i];
            } else {             // batch 0 state is all-zero; or out-of-domain
                own[i] = make_float2(0.f, 0.f);
                prv[i] = make_float2(0.f, 0.f);
                *(float2*)&sB[c] = make_float2(0.f, 0.f);
            }
        }
        __syncthreads();

        // ---- KK substeps, statically ping-ponged ----
        for (int j = 0; j < KK; j += 2) {
            STEP(sA, sB, b * KK + j);
            STEP(sB, sA, b * KK + j + 1);
        }

        // ---- write back 32x32 interior (rows 16..47 -> i in {1,2}) ----
        if (pc >= 8 && pc < 24) {
#pragma unroll
            for (int i = 1; i <= 2; ++i) {
                const int gz = oz + r0 + 16 * i;
                const int gx = ox + lx;
                st_agent(&gout[gz * NXg + gx],     pack2(own[i].x, prv[i].x));
                st_agent(&gout[gz * NXg + gx + 1], pack2(own[i].y, prv[i].y));
            }
        }
        __syncthreads();         // every wave drains vmcnt before s_barrier
        if (tid == 0) {          // publish: data is globally visible already
            __hip_atomic_store(&flags[me], b + 1, __ATOMIC_RELAXED,
                               __HIP_MEMORY_SCOPE_AGENT);
        }
    }
}

extern "C" void kernel_launch(void* const* d_in, const int* in_sizes, int n_in,
                              void* d_out, int out_size, void* d_ws, size_t ws_size,
                              hipStream_t stream) {
    const float* xsrc  = (const float*)d_in[0];
    const float* vel   = (const float*)d_in[1];
    const int*   src_z = (const int*)  d_in[2];
    const int*   src_x = (const int*)  d_in[3];
    const int*   rec_z = (const int*)  d_in[4];
    const int*   rec_x = (const int*)  d_in[5];
    float*       out   = (float*)d_out;

    u64* slot0 = (u64*)d_ws;
    u64* slot1 = slot0 + NZg * NXg;
    int* flags = (int*)(slot1 + NZg * NXg);

    void* args[] = {(void*)&xsrc, (void*)&vel, (void*)&src_z, (void*)&src_x,
                    (void*)&rec_z, (void*)&rec_x, (void*)&out,
                    (void*)&slot0, (void*)&slot1, (void*)&flags};

    dim3 grid(256), block(NTH);
    hipLaunchCooperativeKernel((const void*)wave_nf, grid, block, args, 0, stream);
}

// Round 5
// 899.525 us; speedup vs baseline: 41.2625x; 1.0026x over previous
//
#include <hip/hip_runtime.h>
#include <hip/hip_cooperative_groups.h>

namespace cg = cooperative_groups;

#define NZg  512
#define NXg  512
#define NT   1200
#define NSRC 4
#define NREC 512
#define DTC  0.001f
#define DHC  10.0f

#define TILE   32            // interior tile per block
#define KK     16            // substeps per batch (= halo width), even
#define EE     64            // extended tile = TILE + 2*KK
#define EEP    (EE + 2)      // +2 padding rows (zeroed once)
#define NBATCH 75            // NT / KK
#define NTH    512           // 8 waves

typedef unsigned long long u64;

// Relaxed agent-scope atomics: plain global_load/store with sc0|sc1
// (bypass L1 + non-coherent per-XCD L2; coherent at memory-side L3).
__device__ __forceinline__ u64 ld_agent(const u64* p) {
    return __hip_atomic_load(p, __ATOMIC_RELAXED, __HIP_MEMORY_SCOPE_AGENT);
}
__device__ __forceinline__ void st_agent(u64* p, u64 v) {
    __hip_atomic_store(p, v, __ATOMIC_RELAXED, __HIP_MEMORY_SCOPE_AGENT);
}
__device__ __forceinline__ u64 pack2(float a, float b) {
    union { float f[2]; u64 u; } c; c.f[0] = a; c.f[1] = b; return c.u;
}
__device__ __forceinline__ float2 unpack2(u64 v) {
    union { u64 u; float f[2]; } c; c.u = v; return make_float2(c.f[0], c.f[1]);
}

// Temporal-blocked FDTD, p2p neighbor flag sync, fence-free, 4x2 register
// patches. 256 blocks (16x16 tiles) x 512 threads. Each thread owns a
// 4-wide x 2-tall cell patch: U/D via one ds_read_b128 each, L/R via two
// scalar-pair reads, inter-row vertical neighbors in registers.
__global__ __launch_bounds__(NTH, 1)
void wave_p42(const float* __restrict__ xsrc,   // (NSRC, NT)
              const float* __restrict__ vel,    // (NZ, NX)
              const int*   __restrict__ src_z,
              const int*   __restrict__ src_x,
              const int*   __restrict__ rec_z,
              const int*   __restrict__ rec_x,
              float*       __restrict__ out,    // (NT, NREC)
              u64*         __restrict__ slot0,  // (cur, prev) per cell
              u64*         __restrict__ slot1,
              int*         __restrict__ flags)  // (256)
{
    cg::grid_group grid = cg::this_grid();

    __shared__ float sA[EEP * EE];
    __shared__ float sB[EEP * EE];
    __shared__ float sx[NSRC * NT];
    __shared__ int   recl[NREC];
    __shared__ int   nrec_s;

    const int tid = threadIdx.x;
    const int me  = blockIdx.x;
    const int bz  = me >> 4, bx = me & 15;
    const int oz  = bz * TILE - KK;
    const int ox  = bx * TILE - KK;
    const int pc  = tid & 15;        // patch column: cells 4pc .. 4pc+3
    const int pr  = tid >> 4;        // patch row: tile rows 2pr, 2pr+1
    const int lx  = 4 * pc;
    const int z0  = 2 * pr;          // top tile row of patch
    const int gx  = ox + lx;
    const int gz0 = oz + z0;
    const int gz1 = gz0 + 1;

    // Reset my flag (stale values survive between graph replays).
    if (tid == 0) { flags[me] = 0; nrec_s = 0; }

    // Zero LDS padding rows (rows 0 and EEP-1 of both buffers) once.
    if (tid < 2 * EE) {
        const int r = (tid < EE) ? 0 : (EEP - 1);
        const int c = tid & (EE - 1);
        sA[r * EE + c] = 0.f;  sB[r * EE + c] = 0.f;
    }
    // Stage source traces in LDS.
    for (int i = tid; i < NSRC * NT; i += NTH) sx[i] = xsrc[i];
    __syncthreads();

    // Receiver list for this block's interior.
    for (int r = tid; r < NREC; r += NTH) {
        const int rz = rec_z[r], rx = rec_x[r];
        if (rz >= bz * TILE && rz < bz * TILE + TILE &&
            rx >= bx * TILE && rx < bx * TILE + TILE) {
            const int lzp = rz - oz + 1;          // padded row
            const int lxx = rx - ox;
            const int s = atomicAdd(&nrec_s, 1);
            recl[s] = (r << 16) | (lzp << 8) | lxx;
        }
    }

    // Per-cell coefficients (coef=0 out-of-domain pins those cells to 0)
    // and source bitmask: bit (c*4+s), cells 0..3 top row, 4..7 bottom.
    float4 c0 = make_float4(0.f, 0.f, 0.f, 0.f);
    float4 c1 = c0;
    unsigned int smask = 0;
    {
        int szr[NSRC], sxr[NSRC];
#pragma unroll
        for (int s = 0; s < NSRC; ++s) { szr[s] = src_z[s]; sxr[s] = src_x[s]; }
        float* cc0 = &c0.x;  float* cc1 = &c1.x;
#pragma unroll
        for (int k = 0; k < 4; ++k) {
            const int gxk = gx + k;
            const bool okx = (gxk >= 0 && gxk < NXg);
            if (okx && gz0 >= 0 && gz0 < NZg) {
                const float v = vel[gz0 * NXg + gxk];
                cc0[k] = (v * DTC) * (v * DTC) / (DHC * DHC);
#pragma unroll
                for (int s = 0; s < NSRC; ++s)
                    if (szr[s] == gz0 && sxr[s] == gxk) smask |= 1u << (k * 4 + s);
            }
            if (okx && gz1 >= 0 && gz1 < NZg) {
                const float v = vel[gz1 * NXg + gxk];
                cc1[k] = (v * DTC) * (v * DTC) / (DHC * DHC);
#pragma unroll
                for (int s = 0; s < NSRC; ++s)
                    if (szr[s] == gz1 && sxr[s] == gxk) smask |= 1u << ((4 + k) * 4 + s);
            }
        }
    }
    __syncthreads();
    grid.sync();                 // flags reset everywhere; the ONLY grid sync

    float4 own0, own1, prv0, prv1;
    const int cb0 = (z0 + 1) * EE + lx;          // padded LDS index, top row
    const int cb1 = cb0 + EE;                    // bottom row

    // Neighbor for my spin lane (threads 0..8, skip 4 = self).
    bool havenb = false; int nbidx = 0;
    if (tid < 9 && tid != 4) {
        const int nz = bz + tid / 3 - 1, nx = bx + tid % 3 - 1;
        havenb = (nz >= 0 && nz < 16 && nx >= 0 && nx < 16);
        nbidx  = nz * 16 + nx;
    }

    // One leapfrog substep: read src_, write dst_, then receivers gather.
    auto STEP = [&](float* __restrict__ dst_, const float* __restrict__ src_,
                    int t) {
        const float4 U  = *(const float4*)&src_[cb0 - EE];
        const float4 D  = *(const float4*)&src_[cb1 + EE];
        const float  l0 = src_[cb0 - 1], r0v = src_[cb0 + 4];
        const float  l1 = src_[cb1 - 1], r1v = src_[cb1 + 4];

        float4 n0, n1;
        n0.x = 2.f * own0.x - prv0.x + c0.x * (U.x + own1.x + l0     + own0.y - 4.f * own0.x);
        n0.y = 2.f * own0.y - prv0.y + c0.y * (U.y + own1.y + own0.x + own0.z - 4.f * own0.y);
        n0.z = 2.f * own0.z - prv0.z + c0.z * (U.z + own1.z + own0.y + own0.w - 4.f * own0.z);
        n0.w = 2.f * own0.w - prv0.w + c0.w * (U.w + own1.w + own0.z + r0v    - 4.f * own0.w);
        n1.x = 2.f * own1.x - prv1.x + c1.x * (own0.x + D.x + l1     + own1.y - 4.f * own1.x);
        n1.y = 2.f * own1.y - prv1.y + c1.y * (own0.y + D.y + own1.x + own1.z - 4.f * own1.y);
        n1.z = 2.f * own1.z - prv1.z + c1.z * (own0.z + D.z + own1.y + own1.w - 4.f * own1.z);
        n1.w = 2.f * own1.w - prv1.w + c1.w * (own0.w + D.w + own1.z + r1v    - 4.f * own1.w);

        if (smask) {
            float* pn0 = &n0.x;  float* pn1 = &n1.x;
#pragma unroll
            for (int s = 0; s < NSRC; ++s) {
                const float amp = sx[s * NT + t];
#pragma unroll
                for (int k = 0; k < 4; ++k) {
                    if (smask & (1u << (k * 4 + s)))       pn0[k] += amp;
                    if (smask & (1u << ((4 + k) * 4 + s))) pn1[k] += amp;
                }
            }
        }

        *(float4*)&dst_[cb0] = n0;
        *(float4*)&dst_[cb1] = n1;
        prv0 = own0;  prv1 = own1;
        own0 = n0;    own1 = n1;
        __syncthreads();
        for (int r = tid; r < nrec_s; r += NTH) {
            const int e = recl[r];
            out[t * NREC + (e >> 16)] = dst_[((e >> 8) & 0xFF) * EE + (e & 0xFF)];
        }
    };

    for (int b = 0; b < NBATCH; ++b) {
        const u64* gin  = (b & 1) ? slot1 : slot0;
        u64*       gout = (b & 1) ? slot0 : slot1;

        // ---- wait for the 8 neighbors to have finished batch b-1 ----
        if (b > 0) {
            if (havenb) {
                while (__hip_atomic_load(&flags[nbidx], __ATOMIC_RELAXED,
                                         __HIP_MEMORY_SCOPE_AGENT) < b)
                    __builtin_amdgcn_s_sleep(1);
            }
            __syncthreads();     // spin result broadcast; compiler barrier
        }

        // ---- load extended tile into sB + registers (agent atomics) ----
        {
            float* po0 = &own0.x;  float* pp0 = &prv0.x;
            float* po1 = &own1.x;  float* pp1 = &prv1.x;
#pragma unroll
            for (int k = 0; k < 4; ++k) {
                const int gxk = gx + k;
                const bool okx = (gxk >= 0 && gxk < NXg);
                if (b > 0 && okx && gz0 >= 0 && gz0 < NZg) {
                    const float2 v = unpack2(ld_agent(&gin[gz0 * NXg + gxk]));
                    po0[k] = v.x;  pp0[k] = v.y;
                } else { po0[k] = 0.f;  pp0[k] = 0.f; }
                if (b > 0 && okx && gz1 >= 0 && gz1 < NZg) {
                    const float2 v = unpack2(ld_agent(&gin[gz1 * NXg + gxk]));
                    po1[k] = v.x;  pp1[k] = v.y;
                } else { po1[k] = 0.f;  pp1[k] = 0.f; }
            }
        }
        *(float4*)&sB[cb0] = own0;
        *(float4*)&sB[cb1] = own1;
        __syncthreads();

        // ---- KK substeps, statically ping-ponged ----
        for (int j = 0; j < KK; j += 2) {
            STEP(sA, sB, b * KK + j);
            STEP(sB, sA, b * KK + j + 1);
        }

        // ---- write back 32x32 interior: pr in [8,24), pc in [4,12) ----
        if (pr >= 8 && pr < 24 && pc >= 4 && pc < 12) {
            const float* po0 = &own0.x;  const float* pp0 = &prv0.x;
            const float* po1 = &own1.x;  const float* pp1 = &prv1.x;
#pragma unroll
            for (int k = 0; k < 4; ++k) {
                st_agent(&gout[gz0 * NXg + gx + k], pack2(po0[k], pp0[k]));
                st_agent(&gout[gz1 * NXg + gx + k], pack2(po1[k], pp1[k]));
            }
        }
        __syncthreads();         // every wave drains vmcnt before s_barrier
        if (tid == 0) {          // publish: data is globally visible already
            __hip_atomic_store(&flags[me], b + 1, __ATOMIC_RELAXED,
                               __HIP_MEMORY_SCOPE_AGENT);
        }
    }
}

extern "C" void kernel_launch(void* const* d_in, const int* in_sizes, int n_in,
                              void* d_out, int out_size, void* d_ws, size_t ws_size,
                              hipStream_t stream) {
    const float* xsrc  = (const float*)d_in[0];
    const float* vel   = (const float*)d_in[1];
    const int*   src_z = (const int*)  d_in[2];
    const int*   src_x = (const int*)  d_in[3];
    const int*   rec_z = (const int*)  d_in[4];
    const int*   rec_x = (const int*)  d_in[5];
    float*       out   = (float*)d_out;

    u64* slot0 = (u64*)d_ws;
    u64* slot1 = slot0 + NZg * NXg;
    int* flags = (int*)(slot1 + NZg * NXg);

    void* args[] = {(void*)&xsrc, (void*)&vel, (void*)&src_z, (void*)&src_x,
                    (void*)&rec_z, (void*)&rec_x, (void*)&out,
                    (void*)&slot0, (void*)&slot1, (void*)&flags};

    dim3 grid(256), block(NTH);
    hipLaunchCooperativeKernel((const void*)wave_p42, grid, block, args, 0, stream);
}